// Round 1
// baseline (610.011 us; speedup 1.0000x reference)
//
#include <hip/hip_runtime.h>
#include <hip/hip_fp16.h>

#define VOCAB 32000
#define D 256
#define NSTEPS 12
#define BATCH 8
#define SEQ 512

// scan chunking: chunk 0 = pos [0, CHUNK0) exact; chunk c>=1 covers
// [CHUNK0+(c-1)*CLEN, +CLEN) with WARM warm-up positions from prev=0.
#define CHUNK0 32
#define CLEN 16
#define WARM 16
#define NCHUNK (1 + (SEQ - CHUNK0) / CLEN)   // 31

typedef _Float16 f16x8 __attribute__((ext_vector_type(8)));
typedef float f32x4 __attribute__((ext_vector_type(4)));

__device__ __forceinline__ float gelu_exact(float x) {
    return 0.5f * x * (1.0f + erff(x * 0.70710678118654752440f));
}

// ---------------------------------------------------------------------------
// Phase A: embedding gather + chunked positional scan.
// One block = (chunk, batch). 1024 threads: thread t -> output i = t>>2,
// j-chunk c = t&3 (64 j's each). W rows live in VGPRs (16 float4/thread).
// State [256] f32 in LDS, stored as 4 chunks of 64 padded to 68 f32 so the
// 4 distinct broadcast addresses per ds_read_b128 land on distinct banks.
// ---------------------------------------------------------------------------
__global__ __launch_bounds__(1024) void scan_kernel(
    const int* __restrict__ ids, const float* __restrict__ emb,
    const float* __restrict__ W, const float* __restrict__ ps,
    float* __restrict__ states)
{
    const int chunk = blockIdx.x;
    const int b = blockIdx.y;
    const int t = (int)threadIdx.x;
    const int i = t >> 2;      // output element 0..255
    const int c = t & 3;       // j-chunk 0..3

    // W[i][c*64 + 0..63] in registers
    float4 w[16];
    {
        const float4* wrow = (const float4*)(W + i * D + c * 64);
        #pragma unroll
        for (int r = 0; r < 16; ++r) w[r] = wrow[r];
    }

    __shared__ float sbuf[2][4 * 68];

    int first_out, pstart, pend;
    if (chunk == 0) { first_out = 0; pstart = 0; pend = CHUNK0; }
    else {
        first_out = CHUNK0 + (chunk - 1) * CLEN;
        pstart = first_out - WARM;
        pend = first_out + CLEN;
    }

    float psr[NSTEPS];
    #pragma unroll
    for (int s = 0; s < NSTEPS; ++s) psr[s] = ps[s];

    const int saddr  = c * 68;                      // this thread's read chunk base
    const int myaddr = (i >> 6) * 68 + (i & 63);    // where element i lives

    float prev = 0.0f;

    for (int pos = pstart; pos < pend; ++pos) {
        int id = ids[b * SEQ + pos];
        float ei = emb[(size_t)id * D + i];
        float ctx = (pos > 0) ? (1.0f / (float)(pos + 1)) : 0.0f;
        if (c == 0) sbuf[0][myaddr] = ei;
        __syncthreads();
        float ns = 0.0f;
        #pragma unroll
        for (int s = 0; s < NSTEPS; ++s) {
            const int rb = s & 1;          // read buffer (even steps read buf0)
            float scur = sbuf[rb][myaddr];
            const float4* sc = (const float4*)&sbuf[rb][saddr];
            float ax = 0.f, ay = 0.f, az = 0.f, aw = 0.f;
            #pragma unroll
            for (int r = 0; r < 16; ++r) {
                float4 sv = sc[r];
                ax = fmaf(sv.x, w[r].x, ax);
                ay = fmaf(sv.y, w[r].y, ay);
                az = fmaf(sv.z, w[r].z, az);
                aw = fmaf(sv.w, w[r].w, aw);
            }
            float dot = (ax + ay) + (az + aw);
            dot += __shfl_xor(dot, 1);
            dot += __shfl_xor(dot, 2);     // lanes 0..3 of each group all hold full dot
            float x = fmaf(psr[s], scur, dot);
            ns = gelu_exact(x) + ctx * prev;
            if (c == 0) sbuf[rb ^ 1][myaddr] = ns;
            __syncthreads();
        }
        prev = ns;   // NSTEPS even -> next pos reads/writes buf0 again
        if (pos >= first_out && c == 0)
            states[((size_t)(b * SEQ + pos)) * D + i] = ns;
    }
}

// ---------------------------------------------------------------------------
// Phase B: C[4096][32000] = states @ out_W^T + out_b, f32 via fp16-split MFMA
// (hi*hi + hi*lo + lo*hi), 128x128x64 tiles, 8 waves (2x4), wave tile 64x32.
// LDS tiles XOR-swizzled: byte ^= (row&7)<<4.
// ---------------------------------------------------------------------------
#define BM 128
#define BN 128
#define BK 64
#define GT 512

__device__ __forceinline__ void split8(float4 a, float4 b, f16x8& hi, f16x8& lo) {
    float v[8] = {a.x, a.y, a.z, a.w, b.x, b.y, b.z, b.w};
    #pragma unroll
    for (int j = 0; j < 8; ++j) {
        _Float16 h = (_Float16)v[j];
        hi[j] = h;
        lo[j] = (_Float16)(v[j] - (float)h);
    }
}

__global__ __launch_bounds__(GT) void gemm_kernel(
    const float* __restrict__ A,    // [4096][256] states
    const float* __restrict__ Bw,   // [32000][256] out_W
    const float* __restrict__ bias, // [32000]
    float* __restrict__ C)          // [4096][32000]
{
    __shared__ _Float16 __align__(16) Ahi[BM * BK], Alo[BM * BK];
    __shared__ _Float16 __align__(16) Bhi[BN * BK], Blo[BN * BK];

    const int tid = (int)threadIdx.x;
    const int bn = blockIdx.x, bm = blockIdx.y;
    const int lane = tid & 63, wave = tid >> 6;
    const int wm = wave >> 2, wn = wave & 3;      // 2 x 4 wave grid
    const int l15 = lane & 15, lh = lane >> 4;

    const int sr = tid >> 2;     // staging row 0..127
    const int sg = tid & 3;      // staging k-group (16 f32 each)

    f32x4 acc[4][2] = {};

    for (int kt = 0; kt < D; kt += BK) {
        // ---- stage + split to fp16 hi/lo ----
        {
            const float* asrc = A  + (size_t)(bm * BM + sr) * D + kt + sg * 16;
            const float* bsrc = Bw + (size_t)(bn * BN + sr) * D + kt + sg * 16;
            float4 av[4], bv[4];
            #pragma unroll
            for (int q = 0; q < 4; ++q) {
                av[q] = ((const float4*)asrc)[q];
                bv[q] = ((const float4*)bsrc)[q];
            }
            const int swz = (sr & 7) << 4;
            #pragma unroll
            for (int h = 0; h < 2; ++h) {
                const int off = (sr * 128 + sg * 32 + h * 16) ^ swz;
                f16x8 hi, lo;
                split8(av[h * 2], av[h * 2 + 1], hi, lo);
                *(f16x8*)((char*)Ahi + off) = hi;
                *(f16x8*)((char*)Alo + off) = lo;
                split8(bv[h * 2], bv[h * 2 + 1], hi, lo);
                *(f16x8*)((char*)Bhi + off) = hi;
                *(f16x8*)((char*)Blo + off) = lo;
            }
        }
        __syncthreads();
        // ---- MFMA ----
        #pragma unroll
        for (int ks = 0; ks < 2; ++ks) {
            f16x8 ah[4], al[4], bh[2], bl[2];
            #pragma unroll
            for (int mt = 0; mt < 4; ++mt) {
                const int row = wm * 64 + mt * 16 + l15;
                const int off = (row * 128 + ks * 64 + lh * 16) ^ ((row & 7) << 4);
                ah[mt] = *(const f16x8*)((const char*)Ahi + off);
                al[mt] = *(const f16x8*)((const char*)Alo + off);
            }
            #pragma unroll
            for (int nt = 0; nt < 2; ++nt) {
                const int row = wn * 32 + nt * 16 + l15;
                const int off = (row * 128 + ks * 64 + lh * 16) ^ ((row & 7) << 4);
                bh[nt] = *(const f16x8*)((const char*)Bhi + off);
                bl[nt] = *(const f16x8*)((const char*)Blo + off);
            }
            #pragma unroll
            for (int mt = 0; mt < 4; ++mt)
                #pragma unroll
                for (int nt = 0; nt < 2; ++nt) {
                    acc[mt][nt] = __builtin_amdgcn_mfma_f32_16x16x32_f16(ah[mt], bh[nt], acc[mt][nt], 0, 0, 0);
                    acc[mt][nt] = __builtin_amdgcn_mfma_f32_16x16x32_f16(ah[mt], bl[nt], acc[mt][nt], 0, 0, 0);
                    acc[mt][nt] = __builtin_amdgcn_mfma_f32_16x16x32_f16(al[mt], bh[nt], acc[mt][nt], 0, 0, 0);
                }
        }
        __syncthreads();
    }

    // ---- epilogue: + bias, store f32 ----
    #pragma unroll
    for (int nt = 0; nt < 2; ++nt) {
        const int col = bn * BN + wn * 32 + nt * 16 + l15;
        const float bv = bias[col];
        #pragma unroll
        for (int mt = 0; mt < 4; ++mt) {
            const int row0 = bm * BM + wm * 64 + mt * 16 + lh * 4;
            #pragma unroll
            for (int r = 0; r < 4; ++r)
                C[(size_t)(row0 + r) * VOCAB + col] = acc[mt][nt][r] + bv;
        }
    }
}

extern "C" void kernel_launch(void* const* d_in, const int* in_sizes, int n_in,
                              void* d_out, int out_size, void* d_ws, size_t ws_size,
                              hipStream_t stream)
{
    const int*   ids  = (const int*)d_in[0];
    const float* emb  = (const float*)d_in[1];
    const float* W    = (const float*)d_in[2];
    const float* ps   = (const float*)d_in[3];
    const float* outW = (const float*)d_in[4];
    const float* outb = (const float*)d_in[5];
    float* out    = (float*)d_out;
    float* states = (float*)d_ws;   // [BATCH*SEQ][D] f32 = 4 MB

    scan_kernel<<<dim3(NCHUNK, BATCH), 1024, 0, stream>>>(ids, emb, W, ps, states);
    gemm_kernel<<<dim3(VOCAB / BN, (BATCH * SEQ) / BM), GT, 0, stream>>>(states, outW, outb, out);
}